// Round 4
// baseline (467.401 us; speedup 1.0000x reference)
//
#include <hip/hip_runtime.h>
#include <hip/hip_bf16.h>

// Shapes: N=128, C_IN=C_OUT=64, T=128, V=25, S=3, R=8
// ws layout (bytes):
//   adjfrag (bf16 B-frag) [3][128][64][2 ut][64 lane][8 j]  @ 0           50,331,648
//   w3frag  (bf16 B-frag) [3][2 kb][4 ot][64 lane][8 j]     @ 50,331,648      24,576
//   xT      (bf16) [128][3200 tv][64 c]                     @ 50,356,224  52,428,800
//   xbar    (f32)  [128][64][25]                            @ 102,785,024    819,200
//   partials(f32)  [64 o][2 stat][2048 blk]                 @ 103,604,224  1,048,576
//   stats   (f32)  [128]                                    @ 104,652,800        512
//   coef    (f32)  [64][2]                                  @ 104,653,312        512

typedef __attribute__((ext_vector_type(8))) short bf16x8;
typedef __attribute__((ext_vector_type(4))) float f32x4;

#define X3S 344                 // x3l row stride (elems): 16B-aligned, bank-clean
#define ZR3 (64 * X3S)          // x3l zero row
#define XLZ 200                 // xl zero row index

__device__ inline unsigned short f2bf(float f) {
    union { float f; unsigned int u; } x; x.f = f;
    unsigned int u = x.u;
    return (unsigned short)((u + 0x7FFFu + ((u >> 16) & 1u)) >> 16);
}

__global__ void k_zero(float* xbar) {
    int i = blockIdx.x * 256 + threadIdx.x;
    if (i < 204800) xbar[i] = 0.f;
}

// ---- W3 -> B-fragment-linear bf16 ----
__global__ void k_w3prep(const float* __restrict__ W3, unsigned short* __restrict__ w3f) {
    int g = blockIdx.x * 512 + threadIdx.x;          // 0..1535
    if (g >= 1536) return;
    int grp = g >> 6, lane = g & 63;
    int s = grp >> 3, kb = (grp >> 2) & 1, ot = grp & 3;
    int o = ot * 16 + (lane & 15);
    int c0 = kb * 32 + (lane >> 4) * 8;
    const float* src = W3 + (s * 64 + o) * 64 + c0;
    unsigned int p[4];
#pragma unroll
    for (int e = 0; e < 4; e++)
        p[e] = (unsigned int)f2bf(src[2 * e]) | ((unsigned int)f2bf(src[2 * e + 1]) << 16);
    uint4 v; v.x = p[0]; v.y = p[1]; v.z = p[2]; v.w = p[3];
    *(uint4*)(w3f + (grp * 64 + lane) * 8) = v;
}

// ---- k_prep: one pass over x -> xbar partials (atomic) + transposed bf16 xT ----
__launch_bounds__(256)
__global__ void k_prep(const float* __restrict__ x, float* __restrict__ xbar,
                       unsigned short* __restrict__ xT) {
    __shared__ unsigned short xl[64 * 404];   // 51,712 B -> 3 blocks/CU
    int bid = blockIdx.x;                     // 0..1023
    int n = bid >> 3, tc = bid & 7;
    int tid = threadIdx.x;
    const float* xs = x + (size_t)n * 204800 + tc * 400;
    for (int idx = tid; idx < 6400; idx += 256) {
        int c = idx / 100, r4 = idx - c * 100;
        float4 q = *(const float4*)(xs + c * 3200 + r4 * 4);
        unsigned int lo = (unsigned int)f2bf(q.x) | ((unsigned int)f2bf(q.y) << 16);
        unsigned int hi = (unsigned int)f2bf(q.z) | ((unsigned int)f2bf(q.w) << 16);
        *(uint2*)(xl + c * 404 + r4 * 4) = make_uint2(lo, hi);
    }
    __syncthreads();
    for (int i = tid; i < 1600; i += 256) {
        int c = i / 25, v = i - c * 25;
        float ssum = 0.f;
#pragma unroll
        for (int t = 0; t < 16; t++) {
            unsigned int b = xl[c * 404 + t * 25 + v];
            union { unsigned int u; float f; } cv; cv.u = b << 16;
            ssum += cv.f;
        }
        atomicAdd(&xbar[n * 1600 + i], ssum * (1.f / 128.f));
    }
    unsigned int* out = (unsigned int*)xT + (size_t)n * 102400 + tc * 12800;
    for (int j = tid; j < 12800; j += 256) {
        int cp = j & 31, tv = j >> 5;
        unsigned int lo = xl[(2 * cp) * 404 + tv];
        unsigned int hi = xl[(2 * cp + 1) * 404 + tv];
        out[tv * 32 + cp] = lo | (hi << 16);
    }
}

// ---- K2: adj in B-fragment-linear bf16, zero-padded for u>=25 / v>=25 ----
__global__ void k_adj(const float* __restrict__ xbar,
                      const float* __restrict__ W1, const float* __restrict__ b1,
                      const float* __restrict__ W2, const float* __restrict__ b2,
                      const float* __restrict__ W4, const float* __restrict__ b4,
                      const float* __restrict__ PA, const float* __restrict__ alpha,
                      unsigned short* __restrict__ adjfrag) {
    int sb = blockIdx.x;          // 0..383
    int s = sb >> 7, n = sb & 127;
    __shared__ float xb[1600], w1l[512], w2l[512], w4l[512], b4l[64], pal[625];
    __shared__ float x1l[200], x2l[200];
    __shared__ float dt[8][25][28];
    int tid = threadIdx.x;        // 256
    for (int i = tid; i < 1600; i += 256) xb[i] = xbar[n * 1600 + i];
    for (int i = tid; i < 512; i += 256) {
        w1l[i] = W1[s * 512 + i];
        w2l[i] = W2[s * 512 + i];
        w4l[i] = W4[s * 512 + i];
    }
    if (tid < 64) b4l[tid] = b4[s * 64 + tid];
    for (int i = tid; i < 625; i += 256) pal[i] = PA[s * 625 + i];
    __syncthreads();
    if (tid < 200) {
        int r = tid / 25, v = tid % 25;
        float a1 = b1[s * 8 + r], a2 = b2[s * 8 + r];
        for (int c = 0; c < 64; c++) {
            float xv = xb[c * 25 + v];
            a1 += w1l[r * 64 + c] * xv;
            a2 += w2l[r * 64 + c] * xv;
        }
        x1l[tid] = a1;
        x2l[tid] = a2;
    }
    __syncthreads();
    for (int i = tid; i < 5000; i += 256) {
        int r = i / 625, uv = i % 625, u = uv / 25, v = uv % 25;
        dt[r][u][v] = tanhf(x1l[r * 25 + u] - x2l[r * 25 + v]);
    }
    for (int i = tid; i < 600; i += 256) {
        int r = i / 75, rem = i % 75, u = rem / 3, v = 25 + rem % 3;
        dt[r][u][v] = 0.f;
    }
    __syncthreads();

    int f = tid * 4;
    int lane = (f >> 3) & 63;
    int j0 = f & 7;
    int u = ((f >> 9) << 4) + (lane & 15);
    int v0 = ((lane >> 4) << 3) + j0;
    bool uok = (u < 25);
    float4 dr[8];
    if (uok && v0 < 28) {
#pragma unroll
        for (int r = 0; r < 8; r++) dr[r] = *(const float4*)&dt[r][u][v0];
    } else {
#pragma unroll
        for (int r = 0; r < 8; r++) { dr[r].x = dr[r].y = dr[r].z = dr[r].w = 0.f; }
    }
    float al = alpha[s];
    bool vok[4]; float pae[4];
#pragma unroll
    for (int e = 0; e < 4; e++) {
        int v = v0 + e;
        vok[e] = uok && (v < 25);
        pae[e] = vok[e] ? pal[u * 25 + v] : 0.f;
    }
    unsigned short* outp = adjfrag + ((size_t)(s * 128 + n)) * 65536 + f;
    for (int o = 0; o < 64; o++) {
        float b4o = b4l[o];
        unsigned short q[4];
#pragma unroll
        for (int e = 0; e < 4; e++) {
            float acc = 0.f;
            if (vok[e]) {
                float dot = b4o;
#pragma unroll
                for (int r = 0; r < 8; r++) {
                    float dv = (e == 0) ? dr[r].x : (e == 1) ? dr[r].y : (e == 2) ? dr[r].z : dr[r].w;
                    dot += w4l[o * 8 + r] * dv;
                }
                acc = dot * al + pae[e];
            }
            q[e] = f2bf(acc);
        }
        uint2 pk = make_uint2((unsigned int)q[0] | ((unsigned int)q[1] << 16),
                              (unsigned int)q[2] | ((unsigned int)q[3] << 16));
        *(uint2*)(outp + o * 1024) = pk;
    }
}

// ---- K3: MFMA main. PHASE 0: BN partial sums. PHASE 1: fused BN+res+relu out ----
// block = (n, 8-t chunk), 512 thr, 2048 blocks, 2 blocks/CU.
template<int PHASE>
__launch_bounds__(512, 4)
__global__ void k_main(const unsigned short* __restrict__ xT, const float* __restrict__ b3g,
                       const unsigned short* __restrict__ w3f,
                       const unsigned short* __restrict__ adjf,
                       const float* __restrict__ x, float* __restrict__ outp,
                       float* __restrict__ partials, const float* __restrict__ coef) {
    __shared__ unsigned short xl[201 * 64];        // 25,728 B (row 200 = zeros)
    __shared__ unsigned short x3l[64 * X3S + 48];  // 44,128 B (tail = zero row)
    __shared__ float b3l[192];
    __shared__ float coefl[128];

    int bid = blockIdx.x;                          // 0..2047
    int xcd = bid & 7, j = bid >> 3;
    int tc = j & 15, n = (xcd << 4) | (j >> 4);
    int tid = threadIdx.x;
    int w = tid >> 6, lane = tid & 63, l15 = lane & 15, l4 = lane >> 4;
    int nt = w & 3, mq = w >> 2;

    if (tid < 192) b3l[tid] = b3g[tid];
    if (PHASE == 1 && tid < 128) coefl[tid] = coef[tid];
    if (tid < 32) ((unsigned int*)(xl + XLZ * 64))[tid] = 0u;
    if (tid < 24) ((unsigned int*)(x3l + ZR3))[tid] = 0u;

    // stage x chunk (bf16, XOR-swizzled 16B granules)
    const unsigned short* xTn = xT + ((size_t)n * 3200 + tc * 200) * 64;
    for (int g = tid; g < 1600; g += 512) {
        uint4 q = *(const uint4*)(xTn + g * 8);
        int tv = g >> 3, gg = g & 7;
        *(uint4*)(xl + tv * 64 + ((gg ^ (tv & 7)) << 3)) = q;
    }
    __syncthreads();

    f32x4 zero4 = {0.f, 0.f, 0.f, 0.f};
    f32x4 yacc[16];
#pragma unroll
    for (int i = 0; i < 16; i++) yacc[i] = zero4;

    int vme = mq * 16 + l15;                        // stage-1 A row (v part)
    int rbase = (vme < 25) ? vme : (XLZ * 25 / 25); // row valid flag handled below
    bool vvalid = (vme < 25);

    for (int s = 0; s < 3; s++) {
        const unsigned short* ab = adjf + ((size_t)(s * 128 + n)) * 65536;
        // prefetch ut=0 adj frags (overlaps stage 1)
        bf16x8 bj0[8];
#pragma unroll
        for (int k = 0; k < 8; k++)
            bj0[k] = *(const bf16x8*)(ab + ((size_t)(w * 8 + k) * 2 + 0) * 512 + lane * 8);

        // ---- stage 1: x3 = W3.x + b3 -> x3l ----
        bf16x8 bw0 = *(const bf16x8*)(w3f + ((s * 8 + nt) * 64 + lane) * 8);
        bf16x8 bw1 = *(const bf16x8*)(w3f + ((s * 8 + 4 + nt) * 64 + lane) * 8);
        float bias = b3l[s * 64 + nt * 16 + l15];
#pragma unroll
        for (int i = 0; i < 8; i++) {
            int rr = vvalid ? (i * 25 + vme) : XLZ;
            int sw = rr & 7;
            bf16x8 a0 = *(const bf16x8*)(xl + rr * 64 + ((l4 ^ sw) << 3));
            bf16x8 a1 = *(const bf16x8*)(xl + rr * 64 + (((l4 + 4) ^ sw) << 3));
            f32x4 d = zero4;
            d = __builtin_amdgcn_mfma_f32_16x16x32_bf16(a0, bw0, d, 0, 0, 0);
            d = __builtin_amdgcn_mfma_f32_16x16x32_bf16(a1, bw1, d, 0, 0, 0);
            unsigned int p0 = (unsigned int)f2bf(d[0] + bias) | ((unsigned int)f2bf(d[1] + bias) << 16);
            unsigned int p1 = (unsigned int)f2bf(d[2] + bias) | ((unsigned int)f2bf(d[3] + bias) << 16);
            *(uint2*)(x3l + (nt * 16 + l15) * X3S + i * 40 + mq * 16 + l4 * 4) = make_uint2(p0, p1);
        }
        __syncthreads();

        // ---- stage 2: y += x3 . adjT ----
        bf16x8 afr[8];
#pragma unroll
        for (int k = 0; k < 8; k++) {
            int arow = (l15 < 8) ? ((w * 8 + k) * X3S + l15 * 40) : ZR3;
            afr[k] = *(const bf16x8*)(x3l + arow + l4 * 8);
        }
        bf16x8 bj1[8];
#pragma unroll
        for (int k = 0; k < 8; k++)
            bj1[k] = *(const bf16x8*)(ab + ((size_t)(w * 8 + k) * 2 + 1) * 512 + lane * 8);
#pragma unroll
        for (int k = 0; k < 8; k++)
            yacc[2 * k] = __builtin_amdgcn_mfma_f32_16x16x32_bf16(afr[k], bj0[k], yacc[2 * k], 0, 0, 0);
#pragma unroll
        for (int k = 0; k < 8; k++)
            yacc[2 * k + 1] = __builtin_amdgcn_mfma_f32_16x16x32_bf16(afr[k], bj1[k], yacc[2 * k + 1], 0, 0, 0);
        __syncthreads();
    }

    if (PHASE == 0) {
#pragma unroll
        for (int k = 0; k < 8; k++) {
            int o = w * 8 + k;
            float s1 = 0.f, s2 = 0.f;
#pragma unroll
            for (int ut = 0; ut < 2; ut++) {
                f32x4 d = yacc[2 * k + ut];
#pragma unroll
                for (int r = 0; r < 4; r++) {
                    float val = d[r];
                    s1 += val; s2 += val * val;
                }
            }
#pragma unroll
            for (int off = 1; off < 64; off <<= 1) {
                s1 += __shfl_xor(s1, off);
                s2 += __shfl_xor(s2, off);
            }
            if (lane == 0) {
                partials[((size_t)o * 2 + 0) * 2048 + bid] = s1;
                partials[((size_t)o * 2 + 1) * 2048 + bid] = s2;
            }
        }
    } else {
#pragma unroll
        for (int k = 0; k < 8; k++) {
            int o = w * 8 + k;
            float sc = coefl[o * 2], sh = coefl[o * 2 + 1];
#pragma unroll
            for (int ut = 0; ut < 2; ut++) {
                int u = ut * 16 + l15;
                f32x4 d = yacc[2 * k + ut];
                if (u < 25 && l4 < 2) {
#pragma unroll
                    for (int r = 0; r < 4; r++) {
                        int tg = tc * 8 + l4 * 4 + r;
                        size_t idx = (((size_t)n * 64 + o) * 128 + tg) * 25 + u;
                        outp[idx] = fmaxf(d[r] * sc + sh + x[idx], 0.f);
                    }
                }
            }
        }
    }
}

// ---- reduce partials ----
__global__ void k_reduce(const float* __restrict__ partials, float* __restrict__ stats) {
    int row = blockIdx.x;                    // 0..127
    float a = 0.f;
    for (int i = threadIdx.x; i < 2048; i += 256) a += partials[(size_t)row * 2048 + i];
    for (int off = 32; off; off >>= 1) a += __shfl_down(a, off);
    __shared__ float r4[4];
    int wv = threadIdx.x >> 6, ln = threadIdx.x & 63;
    if (ln == 0) r4[wv] = a;
    __syncthreads();
    if (threadIdx.x == 0) stats[row] = r4[0] + r4[1] + r4[2] + r4[3];
}

__global__ void k_coef(const float* __restrict__ stats, const float* __restrict__ bnw,
                       const float* __restrict__ bnb, float* __restrict__ coef) {
    int o = threadIdx.x;
    if (o < 64) {
        const float inv = 1.f / 409600.f;
        float mean = stats[o * 2] * inv;
        float var = stats[o * 2 + 1] * inv - mean * mean;
        float sc = bnw[o] * rsqrtf(var + 1e-5f);
        coef[o * 2] = sc;
        coef[o * 2 + 1] = bnb[o] - mean * sc;
    }
}

extern "C" void kernel_launch(void* const* d_in, const int* in_sizes, int n_in,
                              void* d_out, int out_size, void* d_ws, size_t ws_size,
                              hipStream_t stream) {
    const float* x    = (const float*)d_in[0];
    const float* W1   = (const float*)d_in[1];
    const float* b1   = (const float*)d_in[2];
    const float* W2   = (const float*)d_in[3];
    const float* b2   = (const float*)d_in[4];
    const float* W3   = (const float*)d_in[5];
    const float* b3   = (const float*)d_in[6];
    const float* W4   = (const float*)d_in[7];
    const float* b4   = (const float*)d_in[8];
    const float* PA   = (const float*)d_in[9];
    const float* alpha= (const float*)d_in[10];
    const float* bnw  = (const float*)d_in[11];
    const float* bnb  = (const float*)d_in[12];

    char* wsb = (char*)d_ws;
    unsigned short* adjfrag = (unsigned short*)wsb;
    unsigned short* w3frag  = (unsigned short*)(wsb + 50331648);
    unsigned short* xT      = (unsigned short*)(wsb + 50356224);
    float* xbar     = (float*)(wsb + 102785024);
    float* partials = (float*)(wsb + 103604224);
    float* stats    = (float*)(wsb + 104652800);
    float* coef     = (float*)(wsb + 104653312);
    float* outp     = (float*)d_out;

    hipLaunchKernelGGL(k_zero, dim3(800), dim3(256), 0, stream, xbar);
    hipLaunchKernelGGL(k_w3prep, dim3(3), dim3(512), 0, stream, W3, w3frag);
    hipLaunchKernelGGL(k_prep, dim3(1024), dim3(256), 0, stream, x, xbar, xT);
    hipLaunchKernelGGL(k_adj, dim3(384), dim3(256), 0, stream,
                       xbar, W1, b1, W2, b2, W4, b4, PA, alpha, adjfrag);
    hipLaunchKernelGGL((k_main<0>), dim3(2048), dim3(512), 0, stream,
                       xT, b3, w3frag, adjfrag, x, outp, partials, coef);
    hipLaunchKernelGGL(k_reduce, dim3(128), dim3(256), 0, stream, partials, stats);
    hipLaunchKernelGGL(k_coef, dim3(1), dim3(64), 0, stream, stats, bnw, bnb, coef);
    hipLaunchKernelGGL((k_main<1>), dim3(2048), dim3(512), 0, stream,
                       xT, b3, w3frag, adjfrag, x, outp, partials, coef);
}

// Round 5
// 224.741 us; speedup vs baseline: 2.0797x; 2.0797x over previous
//
#include <hip/hip_runtime.h>
#include <hip/hip_bf16.h>

// Shapes: N=128, C_IN=C_OUT=64, T=128, V=25, S=3, R=8
// ws layout (bytes):
//   adjfrag (bf16 B-frag) [3][128][64][2 ut][64 lane][8 j]  @ 0           50,331,648
//   w3frag  (bf16 B-frag) [3][2 kb][4 ot][64 lane][8 j]     @ 50,331,648      24,576
//   xT      (bf16) [128][3200 tv][64 c]                     @ 50,356,224  52,428,800
//   xbar    (f32)  [128][64][25]                            @ 102,785,024    819,200
//   partials(f32)  [64 o][2 stat][128 n]                    @ 103,604,224     65,536
//   stats   (f32)  [128]                                    @ 103,669,760        512
//   coef    (f32)  [64][2]                                  @ 103,670,272        512
// y (f32) lives in d_out; k_final updates d_out in place (same-element RMW).

typedef __attribute__((ext_vector_type(8))) short bf16x8;
typedef __attribute__((ext_vector_type(4))) float f32x4;

__device__ inline unsigned short f2bf(float f) {
    union { float f; unsigned int u; } x; x.f = f;
    unsigned int u = x.u;
    return (unsigned short)((u + 0x7FFFu + ((u >> 16) & 1u)) >> 16);
}

__global__ void k_zero(float* xbar) {
    int i = blockIdx.x * 256 + threadIdx.x;
    if (i < 204800) xbar[i] = 0.f;
}

// ---- W3 -> B-fragment-linear bf16 ----
__global__ void k_w3prep(const float* __restrict__ W3, unsigned short* __restrict__ w3f) {
    int g = blockIdx.x * 512 + threadIdx.x;          // 0..1535
    if (g >= 1536) return;
    int grp = g >> 6, lane = g & 63;
    int s = grp >> 3, kb = (grp >> 2) & 1, ot = grp & 3;
    int o = ot * 16 + (lane & 15);
    int c0 = kb * 32 + (lane >> 4) * 8;
    const float* src = W3 + (s * 64 + o) * 64 + c0;
    unsigned int p[4];
#pragma unroll
    for (int e = 0; e < 4; e++)
        p[e] = (unsigned int)f2bf(src[2 * e]) | ((unsigned int)f2bf(src[2 * e + 1]) << 16);
    uint4 v; v.x = p[0]; v.y = p[1]; v.z = p[2]; v.w = p[3];
    *(uint4*)(w3f + (grp * 64 + lane) * 8) = v;
}

// ---- k_prep: one pass over x -> xbar partials (atomic) + transposed bf16 xT ----
__launch_bounds__(256)
__global__ void k_prep(const float* __restrict__ x, float* __restrict__ xbar,
                       unsigned short* __restrict__ xT) {
    __shared__ unsigned short xl[64 * 404];   // 51,712 B -> 3 blocks/CU
    int bid = blockIdx.x;                     // 0..1023
    int n = bid >> 3, tc = bid & 7;
    int tid = threadIdx.x;
    const float* xs = x + (size_t)n * 204800 + tc * 400;
    for (int idx = tid; idx < 6400; idx += 256) {
        int c = idx / 100, r4 = idx - c * 100;
        float4 q = *(const float4*)(xs + c * 3200 + r4 * 4);
        unsigned int lo = (unsigned int)f2bf(q.x) | ((unsigned int)f2bf(q.y) << 16);
        unsigned int hi = (unsigned int)f2bf(q.z) | ((unsigned int)f2bf(q.w) << 16);
        *(uint2*)(xl + c * 404 + r4 * 4) = make_uint2(lo, hi);
    }
    __syncthreads();
    for (int i = tid; i < 1600; i += 256) {
        int c = i / 25, v = i - c * 25;
        float ssum = 0.f;
#pragma unroll
        for (int t = 0; t < 16; t++) {
            unsigned int b = xl[c * 404 + t * 25 + v];
            union { unsigned int u; float f; } cv; cv.u = b << 16;
            ssum += cv.f;
        }
        atomicAdd(&xbar[n * 1600 + i], ssum * (1.f / 128.f));
    }
    unsigned int* out = (unsigned int*)xT + (size_t)n * 102400 + tc * 12800;
    for (int j = tid; j < 12800; j += 256) {
        int cp = j & 31, tv = j >> 5;
        unsigned int lo = xl[(2 * cp) * 404 + tv];
        unsigned int hi = xl[(2 * cp + 1) * 404 + tv];
        out[tv * 32 + cp] = lo | (hi << 16);
    }
}

// ---- K2: adj in B-fragment-linear bf16, zero-padded for u>=25 / v>=25 ----
__global__ void k_adj(const float* __restrict__ xbar,
                      const float* __restrict__ W1, const float* __restrict__ b1,
                      const float* __restrict__ W2, const float* __restrict__ b2,
                      const float* __restrict__ W4, const float* __restrict__ b4,
                      const float* __restrict__ PA, const float* __restrict__ alpha,
                      unsigned short* __restrict__ adjfrag) {
    int sb = blockIdx.x;          // 0..383
    int s = sb >> 7, n = sb & 127;
    __shared__ float xb[1600], w1l[512], w2l[512], w4l[512], b4l[64], pal[625];
    __shared__ float x1l[200], x2l[200];
    __shared__ float dt[8][25][28];
    int tid = threadIdx.x;        // 256
    for (int i = tid; i < 1600; i += 256) xb[i] = xbar[n * 1600 + i];
    for (int i = tid; i < 512; i += 256) {
        w1l[i] = W1[s * 512 + i];
        w2l[i] = W2[s * 512 + i];
        w4l[i] = W4[s * 512 + i];
    }
    if (tid < 64) b4l[tid] = b4[s * 64 + tid];
    for (int i = tid; i < 625; i += 256) pal[i] = PA[s * 625 + i];
    __syncthreads();
    if (tid < 200) {
        int r = tid / 25, v = tid % 25;
        float a1 = b1[s * 8 + r], a2 = b2[s * 8 + r];
        for (int c = 0; c < 64; c++) {
            float xv = xb[c * 25 + v];
            a1 += w1l[r * 64 + c] * xv;
            a2 += w2l[r * 64 + c] * xv;
        }
        x1l[tid] = a1;
        x2l[tid] = a2;
    }
    __syncthreads();
    for (int i = tid; i < 5000; i += 256) {
        int r = i / 625, uv = i % 625, u = uv / 25, v = uv % 25;
        dt[r][u][v] = tanhf(x1l[r * 25 + u] - x2l[r * 25 + v]);
    }
    for (int i = tid; i < 600; i += 256) {
        int r = i / 75, rem = i % 75, u = rem / 3, v = 25 + rem % 3;
        dt[r][u][v] = 0.f;
    }
    __syncthreads();

    int f = tid * 4;
    int lane = (f >> 3) & 63;
    int j0 = f & 7;
    int u = ((f >> 9) << 4) + (lane & 15);
    int v0 = ((lane >> 4) << 3) + j0;
    bool uok = (u < 25);
    float4 dr[8];
    if (uok && v0 < 28) {
#pragma unroll
        for (int r = 0; r < 8; r++) dr[r] = *(const float4*)&dt[r][u][v0];
    } else {
#pragma unroll
        for (int r = 0; r < 8; r++) { dr[r].x = dr[r].y = dr[r].z = dr[r].w = 0.f; }
    }
    float al = alpha[s];
    bool vok[4]; float pae[4];
#pragma unroll
    for (int e = 0; e < 4; e++) {
        int v = v0 + e;
        vok[e] = uok && (v < 25);
        pae[e] = vok[e] ? pal[u * 25 + v] : 0.f;
    }
    unsigned short* outp = adjfrag + ((size_t)(s * 128 + n)) * 65536 + f;
    for (int o = 0; o < 64; o++) {
        float b4o = b4l[o];
        unsigned short q[4];
#pragma unroll
        for (int e = 0; e < 4; e++) {
            float acc = 0.f;
            if (vok[e]) {
                float dot = b4o;
#pragma unroll
                for (int r = 0; r < 8; r++) {
                    float dv = (e == 0) ? dr[r].x : (e == 1) ? dr[r].y : (e == 2) ? dr[r].z : dr[r].w;
                    dot += w4l[o * 8 + r] * dv;
                }
                acc = dot * al + pae[e];
            }
            q[e] = f2bf(acc);
        }
        uint2 pk = make_uint2((unsigned int)q[0] | ((unsigned int)q[1] << 16),
                              (unsigned int)q[2] | ((unsigned int)q[3] << 16));
        *(uint2*)(outp + o * 1024) = pk;
    }
}

// ---- K3: MFMA main, single pass. block=(n, o-slice of 8), t-loop inside.
// adj B-frags register-resident across the whole t loop -> adj HBM = 50 MB total.
__launch_bounds__(512, 4)
__global__ void k_main(const unsigned short* __restrict__ xT, const float* __restrict__ b3g,
                       const unsigned short* __restrict__ w3f,
                       const unsigned short* __restrict__ adjf,
                       float* __restrict__ yg, float* __restrict__ partials) {
    __shared__ unsigned short xl[401 * 64];       // 51,328 B (row 400 = zeros)
    __shared__ unsigned short x3l[16 * 648 + 16]; // 20,832 B
    __shared__ float b3l[192];

    int bid = blockIdx.x;                         // 0..1023
    int n = bid & 127, oq = bid >> 7;             // bid%8 == n%8 -> same-n same-XCD
    int ot = oq >> 1, oh8 = oq & 1;
    int tid = threadIdx.x;
    int w = tid >> 6, lane = tid & 63, l15 = lane & 15, l4 = lane >> 4;
    int o = oq * 8 + w;                           // this wave's output channel
    int o16 = oh8 * 8 + w;                        // column within the 16-o stage-1 tile

    if (tid < 192) b3l[tid] = b3g[tid];
    if (tid < 32) ((unsigned int*)(xl + 400 * 64))[tid] = 0u;

    // register-resident adj B-frags: [s][ut], static indexing via full unroll
    bf16x8 badj[6];
    {
        const unsigned short* ap = adjf + (size_t)n * 65536 + (size_t)o * 1024 + lane * 8;
#pragma unroll
        for (int s = 0; s < 3; s++) {
            badj[s * 2 + 0] = *(const bf16x8*)(ap + (size_t)s * 8388608);
            badj[s * 2 + 1] = *(const bf16x8*)(ap + (size_t)s * 8388608 + 512);
        }
    }

    f32x4 zero4 = {0.f, 0.f, 0.f, 0.f};
    float s1 = 0.f, s2 = 0.f;

    for (int tc = 0; tc < 8; tc++) {
        // stage x chunk (16 t): 3200 16B granules, swizzled
        const unsigned short* xTn = xT + ((size_t)n * 3200 + tc * 400) * 64;
        for (int g = tid; g < 3200; g += 512) {
            uint4 q = *(const uint4*)(xTn + g * 8);
            int tv = g >> 3, gg = g & 7;
            *(uint4*)(xl + tv * 64 + ((gg ^ (tv & 7)) << 3)) = q;
        }
        __syncthreads();

        f32x4 yacc0 = zero4, yacc1 = zero4;
#pragma unroll
        for (int s = 0; s < 3; s++) {
            // ---- stage 1: x3 = W3.x + b3 for the 16-o tile `ot` ----
            bf16x8 bw0 = *(const bf16x8*)(w3f + ((s * 8 + ot) * 64 + lane) * 8);
            bf16x8 bw1 = *(const bf16x8*)(w3f + ((s * 8 + 4 + ot) * 64 + lane) * 8);
            float bias = b3l[s * 64 + ot * 16 + l15];
#pragma unroll
            for (int i = 0; i < 4; i++) {
                int mf = w + 8 * i;               // 32 M-tiles over 8 waves
                int m = mf * 16 + l15;
                int t = m >> 5, v = m & 31;
                int rr = (v < 25) ? (t * 25 + v) : 400;
                int sw = rr & 7;
                bf16x8 a0 = *(const bf16x8*)(xl + rr * 64 + ((l4 ^ sw) << 3));
                bf16x8 a1 = *(const bf16x8*)(xl + rr * 64 + (((l4 + 4) ^ sw) << 3));
                f32x4 d = zero4;
                d = __builtin_amdgcn_mfma_f32_16x16x32_bf16(a0, bw0, d, 0, 0, 0);
                d = __builtin_amdgcn_mfma_f32_16x16x32_bf16(a1, bw1, d, 0, 0, 0);
                int mb = mf * 16 + l4 * 4;
                int td = mb >> 5, vd = mb & 31;
                unsigned int p0 = (unsigned int)f2bf(d[0] + bias) | ((unsigned int)f2bf(d[1] + bias) << 16);
                unsigned int p1 = (unsigned int)f2bf(d[2] + bias) | ((unsigned int)f2bf(d[3] + bias) << 16);
                *(uint2*)(x3l + l15 * 648 + td * 40 + vd) = make_uint2(p0, p1);
            }
            __syncthreads();
            // ---- stage 2: y += x3 . adjT (A row = t = l15, k = v) ----
            {
                bf16x8 a = *(const bf16x8*)(x3l + o16 * 648 + l15 * 40 + l4 * 8);
                yacc0 = __builtin_amdgcn_mfma_f32_16x16x32_bf16(a, badj[s * 2 + 0], yacc0, 0, 0, 0);
                yacc1 = __builtin_amdgcn_mfma_f32_16x16x32_bf16(a, badj[s * 2 + 1], yacc1, 0, 0, 0);
            }
            __syncthreads();
        }

        // ---- per-chunk epilogue: y write (f32 into d_out) + stats accumulate ----
#pragma unroll
        for (int ut = 0; ut < 2; ut++) {
            f32x4 d = (ut == 0) ? yacc0 : yacc1;
            int u = ut * 16 + l15;
#pragma unroll
            for (int r = 0; r < 4; r++) { s1 += d[r]; s2 += d[r] * d[r]; }
            if (u < 25) {
                size_t base = (((size_t)(n * 64 + o) * 128) + tc * 16 + l4 * 4) * 25 + u;
#pragma unroll
                for (int r = 0; r < 4; r++) yg[base + (size_t)r * 25] = d[r];
            }
        }
    }

    // deterministic per-(o,n) partials (no atomics, no zero-init needed)
#pragma unroll
    for (int off = 1; off < 64; off <<= 1) {
        s1 += __shfl_xor(s1, off);
        s2 += __shfl_xor(s2, off);
    }
    if (lane == 0) {
        partials[(o * 2 + 0) * 128 + n] = s1;
        partials[(o * 2 + 1) * 128 + n] = s2;
    }
}

// ---- reduce partials: 128 rows x 128 vals ----
__global__ void k_reduce(const float* __restrict__ partials, float* __restrict__ stats) {
    int row = blockIdx.x;                    // 0..127
    int lane = threadIdx.x;                  // 64
    float a = partials[row * 128 + lane] + partials[row * 128 + 64 + lane];
    for (int off = 32; off; off >>= 1) a += __shfl_down(a, off);
    if (lane == 0) stats[row] = a;
}

__global__ void k_coef(const float* __restrict__ stats, const float* __restrict__ bnw,
                       const float* __restrict__ bnb, float* __restrict__ coef) {
    int o = threadIdx.x;
    if (o < 64) {
        const float inv = 1.f / 409600.f;
        float mean = stats[o * 2] * inv;
        float var = stats[o * 2 + 1] * inv - mean * mean;
        float sc = bnw[o] * rsqrtf(var + 1e-5f);
        coef[o * 2] = sc;
        coef[o * 2 + 1] = bnb[o] - mean * sc;
    }
}

// ---- K5: out = relu(y*scale + shift + x), in place on d_out (same-element RMW) ----
__global__ void k_final(float* __restrict__ y, const float* __restrict__ x,
                        const float* __restrict__ coef) {
    unsigned int i = blockIdx.x * 256u + threadIdx.x;   // 6,553,600 float4 groups
    unsigned int o = (i / 800u) & 63u;
    float sc = coef[o * 2], sh = coef[o * 2 + 1];
    float4 yv = ((const float4*)y)[i];
    float4 xv = ((const float4*)x)[i];
    float4 r;
    r.x = fmaxf(yv.x * sc + sh + xv.x, 0.f);
    r.y = fmaxf(yv.y * sc + sh + xv.y, 0.f);
    r.z = fmaxf(yv.z * sc + sh + xv.z, 0.f);
    r.w = fmaxf(yv.w * sc + sh + xv.w, 0.f);
    ((float4*)y)[i] = r;
}

extern "C" void kernel_launch(void* const* d_in, const int* in_sizes, int n_in,
                              void* d_out, int out_size, void* d_ws, size_t ws_size,
                              hipStream_t stream) {
    const float* x    = (const float*)d_in[0];
    const float* W1   = (const float*)d_in[1];
    const float* b1   = (const float*)d_in[2];
    const float* W2   = (const float*)d_in[3];
    const float* b2   = (const float*)d_in[4];
    const float* W3   = (const float*)d_in[5];
    const float* b3   = (const float*)d_in[6];
    const float* W4   = (const float*)d_in[7];
    const float* b4   = (const float*)d_in[8];
    const float* PA   = (const float*)d_in[9];
    const float* alpha= (const float*)d_in[10];
    const float* bnw  = (const float*)d_in[11];
    const float* bnb  = (const float*)d_in[12];

    char* wsb = (char*)d_ws;
    unsigned short* adjfrag = (unsigned short*)wsb;
    unsigned short* w3frag  = (unsigned short*)(wsb + 50331648);
    unsigned short* xT      = (unsigned short*)(wsb + 50356224);
    float* xbar     = (float*)(wsb + 102785024);
    float* partials = (float*)(wsb + 103604224);
    float* stats    = (float*)(wsb + 103669760);
    float* coef     = (float*)(wsb + 103670272);
    float* yg       = (float*)d_out;

    hipLaunchKernelGGL(k_zero, dim3(800), dim3(256), 0, stream, xbar);
    hipLaunchKernelGGL(k_w3prep, dim3(3), dim3(512), 0, stream, W3, w3frag);
    hipLaunchKernelGGL(k_prep, dim3(1024), dim3(256), 0, stream, x, xbar, xT);
    hipLaunchKernelGGL(k_adj, dim3(384), dim3(256), 0, stream,
                       xbar, W1, b1, W2, b2, W4, b4, PA, alpha, adjfrag);
    hipLaunchKernelGGL(k_main, dim3(1024), dim3(512), 0, stream,
                       xT, b3, w3frag, adjfrag, yg, partials);
    hipLaunchKernelGGL(k_reduce, dim3(128), dim3(64), 0, stream, partials, stats);
    hipLaunchKernelGGL(k_coef, dim3(1), dim3(64), 0, stream, stats, bnw, bnb, coef);
    hipLaunchKernelGGL(k_final, dim3(25600), dim3(256), 0, stream, yg, x, coef);
}

// Round 6
// 212.264 us; speedup vs baseline: 2.2020x; 1.0588x over previous
//
#include <hip/hip_runtime.h>
#include <hip/hip_bf16.h>

// Shapes: N=128, C_IN=C_OUT=64, T=128, V=25, S=3, R=8
// ws layout (bytes):
//   adjfrag (bf16 B-frag) [3][128][64][2 ut][64 lane][8 j]  @ 0           50,331,648
//   w3frag  (bf16 B-frag) [3][2 kb][4 ot][64 lane][8 j]     @ 50,331,648      24,576
//   xT      (bf16) [128][3200 tv][64 c]                     @ 50,356,224  52,428,800
//   xbar    (f32)  [128][64][25]                            @ 102,785,024    819,200
//   partials(f32)  [64 o][2 stat][128 n]                    @ 103,604,224     65,536
//   coef    (f32)  [64][2]                                  @ 103,669,760        512
// y (f32) lives in d_out; k_final updates d_out in place (same-element RMW).

typedef __attribute__((ext_vector_type(8))) short bf16x8;
typedef __attribute__((ext_vector_type(4))) float f32x4;

__device__ inline unsigned short f2bf(float f) {
    union { float f; unsigned int u; } x; x.f = f;
    unsigned int u = x.u;
    return (unsigned short)((u + 0x7FFFu + ((u >> 16) & 1u)) >> 16);
}

__global__ void k_zero(float* xbar) {
    int i = blockIdx.x * 256 + threadIdx.x;
    if (i < 204800) xbar[i] = 0.f;
}

// ---- W3 -> B-fragment-linear bf16 ----
__global__ void k_w3prep(const float* __restrict__ W3, unsigned short* __restrict__ w3f) {
    int g = blockIdx.x * 512 + threadIdx.x;          // 0..1535
    if (g >= 1536) return;
    int grp = g >> 6, lane = g & 63;
    int s = grp >> 3, kb = (grp >> 2) & 1, ot = grp & 3;
    int o = ot * 16 + (lane & 15);
    int c0 = kb * 32 + (lane >> 4) * 8;
    const float* src = W3 + (s * 64 + o) * 64 + c0;
    unsigned int p[4];
#pragma unroll
    for (int e = 0; e < 4; e++)
        p[e] = (unsigned int)f2bf(src[2 * e]) | ((unsigned int)f2bf(src[2 * e + 1]) << 16);
    uint4 v; v.x = p[0]; v.y = p[1]; v.z = p[2]; v.w = p[3];
    *(uint4*)(w3f + (grp * 64 + lane) * 8) = v;
}

// ---- k_prep: one pass over x -> xbar partials (atomic) + transposed bf16 xT ----
__launch_bounds__(512)
__global__ void k_prep(const float* __restrict__ x, float* __restrict__ xbar,
                       unsigned short* __restrict__ xT) {
    __shared__ unsigned short xl[64 * 404];   // 51,712 B -> 3 blocks/CU
    int bid = blockIdx.x;                     // 0..1023
    int n = bid >> 3, tc = bid & 7;
    int tid = threadIdx.x;                    // 512
    const float* xs = x + (size_t)n * 204800 + tc * 400;
    for (int idx = tid; idx < 6400; idx += 512) {
        int c = idx / 100, r4 = idx - c * 100;
        float4 q = *(const float4*)(xs + c * 3200 + r4 * 4);
        unsigned int lo = (unsigned int)f2bf(q.x) | ((unsigned int)f2bf(q.y) << 16);
        unsigned int hi = (unsigned int)f2bf(q.z) | ((unsigned int)f2bf(q.w) << 16);
        *(uint2*)(xl + c * 404 + r4 * 4) = make_uint2(lo, hi);
    }
    __syncthreads();
    for (int i = tid; i < 1600; i += 512) {
        int c = i / 25, v = i - c * 25;
        float ssum = 0.f;
#pragma unroll
        for (int t = 0; t < 16; t++) {
            unsigned int b = xl[c * 404 + t * 25 + v];
            union { unsigned int u; float f; } cv; cv.u = b << 16;
            ssum += cv.f;
        }
        atomicAdd(&xbar[n * 1600 + i], ssum * (1.f / 128.f));
    }
    unsigned int* out = (unsigned int*)xT + (size_t)n * 102400 + tc * 12800;
    for (int j = tid; j < 12800; j += 512) {
        int cp = j & 31, tv = j >> 5;
        unsigned int lo = xl[(2 * cp) * 404 + tv];
        unsigned int hi = xl[(2 * cp + 1) * 404 + tv];
        out[tv * 32 + cp] = lo | (hi << 16);
    }
}

// ---- K2: adj in B-fragment-linear bf16, zero-padded for u>=25 / v>=25 ----
__global__ void k_adj(const float* __restrict__ xbar,
                      const float* __restrict__ W1, const float* __restrict__ b1,
                      const float* __restrict__ W2, const float* __restrict__ b2,
                      const float* __restrict__ W4, const float* __restrict__ b4,
                      const float* __restrict__ PA, const float* __restrict__ alpha,
                      unsigned short* __restrict__ adjfrag) {
    int sb = blockIdx.x;          // 0..383
    int s = sb >> 7, n = sb & 127;
    __shared__ float xb[1600], w1l[512], w2l[512], w4l[512], b4l[64], pal[625];
    __shared__ float x1l[200], x2l[200];
    __shared__ float dt[8][25][28];
    int tid = threadIdx.x;        // 256
    for (int i = tid; i < 1600; i += 256) xb[i] = xbar[n * 1600 + i];
    for (int i = tid; i < 512; i += 256) {
        w1l[i] = W1[s * 512 + i];
        w2l[i] = W2[s * 512 + i];
        w4l[i] = W4[s * 512 + i];
    }
    if (tid < 64) b4l[tid] = b4[s * 64 + tid];
    for (int i = tid; i < 625; i += 256) pal[i] = PA[s * 625 + i];
    __syncthreads();
    if (tid < 200) {
        int r = tid / 25, v = tid % 25;
        float a1 = b1[s * 8 + r], a2 = b2[s * 8 + r];
        for (int c = 0; c < 64; c++) {
            float xv = xb[c * 25 + v];
            a1 += w1l[r * 64 + c] * xv;
            a2 += w2l[r * 64 + c] * xv;
        }
        x1l[tid] = a1;
        x2l[tid] = a2;
    }
    __syncthreads();
    for (int i = tid; i < 5000; i += 256) {
        int r = i / 625, uv = i % 625, u = uv / 25, v = uv % 25;
        dt[r][u][v] = tanhf(x1l[r * 25 + u] - x2l[r * 25 + v]);
    }
    for (int i = tid; i < 600; i += 256) {
        int r = i / 75, rem = i % 75, u = rem / 3, v = 25 + rem % 3;
        dt[r][u][v] = 0.f;
    }
    __syncthreads();

    int f = tid * 4;
    int lane = (f >> 3) & 63;
    int j0 = f & 7;
    int u = ((f >> 9) << 4) + (lane & 15);
    int v0 = ((lane >> 4) << 3) + j0;
    bool uok = (u < 25);
    float4 dr[8];
    if (uok && v0 < 28) {
#pragma unroll
        for (int r = 0; r < 8; r++) dr[r] = *(const float4*)&dt[r][u][v0];
    } else {
#pragma unroll
        for (int r = 0; r < 8; r++) { dr[r].x = dr[r].y = dr[r].z = dr[r].w = 0.f; }
    }
    float al = alpha[s];
    bool vok[4]; float pae[4];
#pragma unroll
    for (int e = 0; e < 4; e++) {
        int v = v0 + e;
        vok[e] = uok && (v < 25);
        pae[e] = vok[e] ? pal[u * 25 + v] : 0.f;
    }
    unsigned short* outp = adjfrag + ((size_t)(s * 128 + n)) * 65536 + f;
    for (int o = 0; o < 64; o++) {
        float b4o = b4l[o];
        unsigned short q[4];
#pragma unroll
        for (int e = 0; e < 4; e++) {
            float acc = 0.f;
            if (vok[e]) {
                float dot = b4o;
#pragma unroll
                for (int r = 0; r < 8; r++) {
                    float dv = (e == 0) ? dr[r].x : (e == 1) ? dr[r].y : (e == 2) ? dr[r].z : dr[r].w;
                    dot += w4l[o * 8 + r] * dv;
                }
                acc = dot * al + pae[e];
            }
            q[e] = f2bf(acc);
        }
        uint2 pk = make_uint2((unsigned int)q[0] | ((unsigned int)q[1] << 16),
                              (unsigned int)q[2] | ((unsigned int)q[3] << 16));
        *(uint2*)(outp + o * 1024) = pk;
    }
}

// ---- K3: MFMA main, deduped. block = (n, 16-o tile), t-loop inside.
// Stage 1 computed ONCE per (n, ot); each wave owns 2 o's in stage 2.
// adj B-frags (12) register-resident across the whole t loop.
__launch_bounds__(512, 4)
__global__ void k_main(const unsigned short* __restrict__ xT, const float* __restrict__ b3g,
                       const unsigned short* __restrict__ w3f,
                       const unsigned short* __restrict__ adjf,
                       float* __restrict__ yg, float* __restrict__ partials) {
    __shared__ unsigned short xl[401 * 64];       // 51,328 B (row 400 = zeros)
    __shared__ unsigned short x3l[16 * 648];      // 20,736 B
    __shared__ float b3l[192];

    int bid = blockIdx.x;                         // 0..511
    int n = bid & 127, ot = bid >> 7;             // same-n blocks -> same XCD
    int tid = threadIdx.x;
    int w = tid >> 6, lane = tid & 63, l15 = lane & 15, l4 = lane >> 4;
    int oa = ot * 16 + 2 * w;                     // this wave's first output channel

    if (tid < 192) b3l[tid] = b3g[tid];
    if (tid < 32) ((unsigned int*)(xl + 400 * 64))[tid] = 0u;

    // 12 register-resident adj B-frags: [s][oj][ut], static indexing
    bf16x8 badj[12];
    {
        const unsigned short* ap = adjf + (size_t)n * 65536 + (size_t)oa * 1024 + lane * 8;
#pragma unroll
        for (int s = 0; s < 3; s++)
#pragma unroll
            for (int oj = 0; oj < 2; oj++)
#pragma unroll
                for (int ut = 0; ut < 2; ut++)
                    badj[s * 4 + oj * 2 + ut] =
                        *(const bf16x8*)(ap + (size_t)s * 8388608 + oj * 1024 + ut * 512);
    }

    f32x4 zero4 = {0.f, 0.f, 0.f, 0.f};
    float s1[2] = {0.f, 0.f}, s2[2] = {0.f, 0.f};

    for (int tc = 0; tc < 8; tc++) {
        // stage x chunk (16 t): 3200 16B granules, swizzled
        const unsigned short* xTn = xT + ((size_t)n * 3200 + tc * 400) * 64;
        for (int g = tid; g < 3200; g += 512) {
            uint4 q = *(const uint4*)(xTn + g * 8);
            int tv = g >> 3, gg = g & 7;
            *(uint4*)(xl + tv * 64 + ((gg ^ (tv & 7)) << 3)) = q;
        }
        __syncthreads();

        f32x4 yacc[4] = {zero4, zero4, zero4, zero4};
#pragma unroll
        for (int s = 0; s < 3; s++) {
            // ---- stage 1: x3 = W3.x + b3 for the 16-o tile (once per block) ----
            bf16x8 bw0 = *(const bf16x8*)(w3f + ((s * 8 + ot) * 64 + lane) * 8);
            bf16x8 bw1 = *(const bf16x8*)(w3f + ((s * 8 + 4 + ot) * 64 + lane) * 8);
            float bias = b3l[s * 64 + ot * 16 + l15];
#pragma unroll
            for (int i = 0; i < 4; i++) {
                int mf = w + 8 * i;               // 32 M-tiles over 8 waves
                int m = mf * 16 + l15;
                int t = m >> 5, v = m & 31;
                int rr = (v < 25) ? (t * 25 + v) : 400;
                int sw = rr & 7;
                bf16x8 a0 = *(const bf16x8*)(xl + rr * 64 + ((l4 ^ sw) << 3));
                bf16x8 a1 = *(const bf16x8*)(xl + rr * 64 + (((l4 + 4) ^ sw) << 3));
                f32x4 d = zero4;
                d = __builtin_amdgcn_mfma_f32_16x16x32_bf16(a0, bw0, d, 0, 0, 0);
                d = __builtin_amdgcn_mfma_f32_16x16x32_bf16(a1, bw1, d, 0, 0, 0);
                int mb = mf * 16 + l4 * 4;
                int td = mb >> 5, vd = mb & 31;
                unsigned int p0 = (unsigned int)f2bf(d[0] + bias) | ((unsigned int)f2bf(d[1] + bias) << 16);
                unsigned int p1 = (unsigned int)f2bf(d[2] + bias) | ((unsigned int)f2bf(d[3] + bias) << 16);
                *(uint2*)(x3l + l15 * 648 + td * 40 + vd) = make_uint2(p0, p1);
            }
            __syncthreads();
            // ---- stage 2: y += x3 . adjT for this wave's o-pair ----
            {
                bf16x8 aA = *(const bf16x8*)(x3l + (2 * w) * 648 + l15 * 40 + l4 * 8);
                bf16x8 aB = *(const bf16x8*)(x3l + (2 * w + 1) * 648 + l15 * 40 + l4 * 8);
                yacc[0] = __builtin_amdgcn_mfma_f32_16x16x32_bf16(aA, badj[s * 4 + 0], yacc[0], 0, 0, 0);
                yacc[1] = __builtin_amdgcn_mfma_f32_16x16x32_bf16(aA, badj[s * 4 + 1], yacc[1], 0, 0, 0);
                yacc[2] = __builtin_amdgcn_mfma_f32_16x16x32_bf16(aB, badj[s * 4 + 2], yacc[2], 0, 0, 0);
                yacc[3] = __builtin_amdgcn_mfma_f32_16x16x32_bf16(aB, badj[s * 4 + 3], yacc[3], 0, 0, 0);
            }
            __syncthreads();
        }

        // ---- per-chunk epilogue: y write (f32 into d_out) + stats accumulate ----
#pragma unroll
        for (int oj = 0; oj < 2; oj++) {
            int o = oa + oj;
#pragma unroll
            for (int ut = 0; ut < 2; ut++) {
                f32x4 d = yacc[oj * 2 + ut];
                int u = ut * 16 + l15;
#pragma unroll
                for (int r = 0; r < 4; r++) { s1[oj] += d[r]; s2[oj] += d[r] * d[r]; }
                if (u < 25) {
                    size_t base = (((size_t)(n * 64 + o) * 128) + tc * 16 + l4 * 4) * 25 + u;
#pragma unroll
                    for (int r = 0; r < 4; r++) yg[base + (size_t)r * 25] = d[r];
                }
            }
        }
    }

    // deterministic per-(o,n) partials
#pragma unroll
    for (int oj = 0; oj < 2; oj++) {
        float a = s1[oj], b = s2[oj];
#pragma unroll
        for (int off = 1; off < 64; off <<= 1) {
            a += __shfl_xor(a, off);
            b += __shfl_xor(b, off);
        }
        if (lane == 0) {
            partials[((oa + oj) * 2 + 0) * 128 + n] = a;
            partials[((oa + oj) * 2 + 1) * 128 + n] = b;
        }
    }
}

// ---- fused reduce + coef: one block, 128 threads ----
__global__ void k_redcoef(const float* __restrict__ partials, const float* __restrict__ bnw,
                          const float* __restrict__ bnb, float* __restrict__ coef) {
    __shared__ float st[128];
    int tid = threadIdx.x;                   // 128
    const float4* p = (const float4*)(partials + tid * 128);
    float a = 0.f;
#pragma unroll
    for (int i = 0; i < 32; i++) {
        float4 q = p[i];
        a += q.x + q.y + q.z + q.w;
    }
    st[tid] = a;
    __syncthreads();
    if (tid < 64) {
        const float inv = 1.f / 409600.f;
        float mean = st[2 * tid] * inv;
        float var = st[2 * tid + 1] * inv - mean * mean;
        float sc = bnw[tid] * rsqrtf(var + 1e-5f);
        coef[2 * tid] = sc;
        coef[2 * tid + 1] = bnb[tid] - mean * sc;
    }
}

// ---- K5: out = relu(y*scale + shift + x), in place on d_out (same-element RMW) ----
__launch_bounds__(512)
__global__ void k_final(float* __restrict__ y, const float* __restrict__ x,
                        const float* __restrict__ coef) {
    unsigned int i = blockIdx.x * 512u + threadIdx.x;   // 6,553,600 float4 groups
    unsigned int o = (i / 800u) & 63u;
    float sc = coef[o * 2], sh = coef[o * 2 + 1];
    float4 yv = ((const float4*)y)[i];
    float4 xv = ((const float4*)x)[i];
    float4 r;
    r.x = fmaxf(yv.x * sc + sh + xv.x, 0.f);
    r.y = fmaxf(yv.y * sc + sh + xv.y, 0.f);
    r.z = fmaxf(yv.z * sc + sh + xv.z, 0.f);
    r.w = fmaxf(yv.w * sc + sh + xv.w, 0.f);
    ((float4*)y)[i] = r;
}

extern "C" void kernel_launch(void* const* d_in, const int* in_sizes, int n_in,
                              void* d_out, int out_size, void* d_ws, size_t ws_size,
                              hipStream_t stream) {
    const float* x    = (const float*)d_in[0];
    const float* W1   = (const float*)d_in[1];
    const float* b1   = (const float*)d_in[2];
    const float* W2   = (const float*)d_in[3];
    const float* b2   = (const float*)d_in[4];
    const float* W3   = (const float*)d_in[5];
    const float* b3   = (const float*)d_in[6];
    const float* W4   = (const float*)d_in[7];
    const float* b4   = (const float*)d_in[8];
    const float* PA   = (const float*)d_in[9];
    const float* alpha= (const float*)d_in[10];
    const float* bnw  = (const float*)d_in[11];
    const float* bnb  = (const float*)d_in[12];

    char* wsb = (char*)d_ws;
    unsigned short* adjfrag = (unsigned short*)wsb;
    unsigned short* w3frag  = (unsigned short*)(wsb + 50331648);
    unsigned short* xT      = (unsigned short*)(wsb + 50356224);
    float* xbar     = (float*)(wsb + 102785024);
    float* partials = (float*)(wsb + 103604224);
    float* coef     = (float*)(wsb + 103669760);
    float* yg       = (float*)d_out;

    hipLaunchKernelGGL(k_zero, dim3(800), dim3(256), 0, stream, xbar);
    hipLaunchKernelGGL(k_w3prep, dim3(3), dim3(512), 0, stream, W3, w3frag);
    hipLaunchKernelGGL(k_prep, dim3(1024), dim3(512), 0, stream, x, xbar, xT);
    hipLaunchKernelGGL(k_adj, dim3(384), dim3(256), 0, stream,
                       xbar, W1, b1, W2, b2, W4, b4, PA, alpha, adjfrag);
    hipLaunchKernelGGL(k_main, dim3(512), dim3(512), 0, stream,
                       xT, b3, w3frag, adjfrag, yg, partials);
    hipLaunchKernelGGL(k_redcoef, dim3(1), dim3(128), 0, stream, partials, bnw, bnb, coef);
    hipLaunchKernelGGL(k_final, dim3(12800), dim3(512), 0, stream, yg, x, coef);
}

// Round 7
// 147.226 us; speedup vs baseline: 3.1747x; 1.4418x over previous
//
#include <hip/hip_runtime.h>
#include <hip/hip_bf16.h>

// Shapes: N=128, C_IN=C_OUT=64, T=128, V=25, S=3, R=8
// ws layout (bytes) — all matrices fp8 e4m3:
//   adjfrag [3][128][64 o][2 ut][64 lane][8 j]   @ 0           25,165,824
//   w3frag  [3][2 kb][4 ot][64 lane][8 j]        @ 25,165,824      12,288
//   xT      [128][3200 tv][64 c]                 @ 25,178,112  26,214,400
//   y8      [128][64][128 t][25 u]               @ 51,392,512  26,214,400
//   xbar f32 [128][64][25]                       @ 77,606,912     819,200
//   partials f32 [64 o][2 stat][128 n]           @ 78,426,112      65,536
//   coef f32 [64][2]                             @ 78,491,648         512

typedef __attribute__((ext_vector_type(4))) float f32x4;
typedef __attribute__((ext_vector_type(2))) float f32x2;
typedef long long i64;

#define ADJ8_OFF  0
#define W3F8_OFF  25165824
#define XT8_OFF   25178112
#define Y8_OFF    51392512
#define XBAR_OFF  77606912
#define PART_OFF  78426112
#define COEF_OFF  78491648

__device__ inline unsigned short f2bf(float f) {
    union { float f; unsigned int u; } x; x.f = f;
    unsigned int u = x.u;
    return (unsigned short)((u + 0x7FFFu + ((u >> 16) & 1u)) >> 16);
}

__global__ void k_zero(float* xbar) {
    int i = blockIdx.x * 256 + threadIdx.x;
    if (i < 204800) xbar[i] = 0.f;
}

// ---- W3 -> B-fragment-linear fp8 ----
__global__ void k_w3prep(const float* __restrict__ W3, unsigned char* __restrict__ w3f) {
    int g = blockIdx.x * 512 + threadIdx.x;          // 0..1535
    if (g >= 1536) return;
    int grp = g >> 6, lane = g & 63;
    int s = grp >> 3, kb = (grp >> 2) & 1, ot = grp & 3;
    int o = ot * 16 + (lane & 15);
    int c0 = kb * 32 + (lane >> 4) * 8;
    const float* src = W3 + (s * 64 + o) * 64 + c0;
    unsigned int p0 = __builtin_amdgcn_cvt_pk_fp8_f32(src[0], src[1], 0, false);
    p0 = __builtin_amdgcn_cvt_pk_fp8_f32(src[2], src[3], p0, true);
    unsigned int p1 = __builtin_amdgcn_cvt_pk_fp8_f32(src[4], src[5], 0, false);
    p1 = __builtin_amdgcn_cvt_pk_fp8_f32(src[6], src[7], p1, true);
    *(uint2*)(w3f + (grp * 64 + lane) * 8) = make_uint2(p0, p1);
}

// ---- k_prep: one pass over x -> xbar partials (atomic) + transposed fp8 xT ----
__launch_bounds__(512)
__global__ void k_prep(const float* __restrict__ x, float* __restrict__ xbar,
                       unsigned char* __restrict__ xT) {
    __shared__ unsigned short xl[64 * 404];   // bf16, 51,712 B -> 3 blocks/CU
    int bid = blockIdx.x;                     // 0..1023
    int n = bid >> 3, tc = bid & 7;
    int tid = threadIdx.x;                    // 512
    const float* xs = x + (size_t)n * 204800 + tc * 400;
    for (int idx = tid; idx < 6400; idx += 512) {
        int c = idx / 100, r4 = idx - c * 100;
        float4 q = *(const float4*)(xs + c * 3200 + r4 * 4);
        unsigned int lo = (unsigned int)f2bf(q.x) | ((unsigned int)f2bf(q.y) << 16);
        unsigned int hi = (unsigned int)f2bf(q.z) | ((unsigned int)f2bf(q.w) << 16);
        *(uint2*)(xl + c * 404 + r4 * 4) = make_uint2(lo, hi);
    }
    __syncthreads();
    for (int i = tid; i < 1600; i += 512) {
        int c = i / 25, v = i - c * 25;
        float ssum = 0.f;
#pragma unroll
        for (int t = 0; t < 16; t++) {
            unsigned int b = xl[c * 404 + t * 25 + v];
            union { unsigned int u; float f; } cv; cv.u = b << 16;
            ssum += cv.f;
        }
        atomicAdd(&xbar[n * 1600 + i], ssum * (1.f / 128.f));
    }
    unsigned int* out = (unsigned int*)(xT) + (size_t)n * 51200 + tc * 6400;
    for (int j = tid; j < 6400; j += 512) {
        int cq = j & 15, tv = j >> 4;
        float f[4];
#pragma unroll
        for (int e = 0; e < 4; e++) {
            unsigned int b = xl[(4 * cq + e) * 404 + tv];
            union { unsigned int u; float g; } cv; cv.u = b << 16;
            f[e] = cv.g;
        }
        unsigned int pk = __builtin_amdgcn_cvt_pk_fp8_f32(f[0], f[1], 0, false);
        pk = __builtin_amdgcn_cvt_pk_fp8_f32(f[2], f[3], pk, true);
        out[j] = pk;
    }
}

// ---- K2: adj in B-fragment-linear fp8, zero-padded for u>=25 / v>=25 ----
__global__ void k_adj(const float* __restrict__ xbar,
                      const float* __restrict__ W1, const float* __restrict__ b1,
                      const float* __restrict__ W2, const float* __restrict__ b2,
                      const float* __restrict__ W4, const float* __restrict__ b4,
                      const float* __restrict__ PA, const float* __restrict__ alpha,
                      unsigned char* __restrict__ adjf) {
    int sb = blockIdx.x;          // 0..383
    int s = sb >> 7, n = sb & 127;
    __shared__ float xb[1600], w1l[512], w2l[512], w4l[512], b4l[64], pal[625];
    __shared__ float x1l[200], x2l[200];
    __shared__ float dt[8][25][28];
    int tid = threadIdx.x;        // 256
    for (int i = tid; i < 1600; i += 256) xb[i] = xbar[n * 1600 + i];
    for (int i = tid; i < 512; i += 256) {
        w1l[i] = W1[s * 512 + i];
        w2l[i] = W2[s * 512 + i];
        w4l[i] = W4[s * 512 + i];
    }
    if (tid < 64) b4l[tid] = b4[s * 64 + tid];
    for (int i = tid; i < 625; i += 256) pal[i] = PA[s * 625 + i];
    __syncthreads();
    if (tid < 200) {
        int r = tid / 25, v = tid % 25;
        float a1 = b1[s * 8 + r], a2 = b2[s * 8 + r];
        for (int c = 0; c < 64; c++) {
            float xv = xb[c * 25 + v];
            a1 += w1l[r * 64 + c] * xv;
            a2 += w2l[r * 64 + c] * xv;
        }
        x1l[tid] = a1;
        x2l[tid] = a2;
    }
    __syncthreads();
    for (int i = tid; i < 5000; i += 256) {
        int r = i / 625, uv = i % 625, u = uv / 25, v = uv % 25;
        dt[r][u][v] = tanhf(x1l[r * 25 + u] - x2l[r * 25 + v]);
    }
    for (int i = tid; i < 600; i += 256) {
        int r = i / 75, rem = i % 75, u = rem / 3, v = 25 + rem % 3;
        dt[r][u][v] = 0.f;
    }
    __syncthreads();

    int f = tid * 4;                 // byte offset within the 1024-B o-row
    int lane = (f >> 3) & 63;
    int j0 = f & 7;
    int u = ((f >> 9) << 4) + (lane & 15);
    int v0 = ((lane >> 4) << 3) + j0;
    bool uok = (u < 25);
    float4 dr[8];
    if (uok && v0 < 28) {
#pragma unroll
        for (int r = 0; r < 8; r++) dr[r] = *(const float4*)&dt[r][u][v0];
    } else {
#pragma unroll
        for (int r = 0; r < 8; r++) { dr[r].x = dr[r].y = dr[r].z = dr[r].w = 0.f; }
    }
    float al = alpha[s];
    bool vok[4]; float pae[4];
#pragma unroll
    for (int e = 0; e < 4; e++) {
        int v = v0 + e;
        vok[e] = uok && (v < 25);
        pae[e] = vok[e] ? pal[u * 25 + v] : 0.f;
    }
    unsigned char* outp = adjf + ((size_t)(s * 128 + n)) * 65536 + f;
    for (int o = 0; o < 64; o++) {
        float b4o = b4l[o];
        float acc[4];
#pragma unroll
        for (int e = 0; e < 4; e++) {
            acc[e] = 0.f;
            if (vok[e]) {
                float dot = b4o;
#pragma unroll
                for (int r = 0; r < 8; r++) {
                    float dv = (e == 0) ? dr[r].x : (e == 1) ? dr[r].y : (e == 2) ? dr[r].z : dr[r].w;
                    dot += w4l[o * 8 + r] * dv;
                }
                acc[e] = dot * al + pae[e];
            }
        }
        unsigned int pk = __builtin_amdgcn_cvt_pk_fp8_f32(acc[0], acc[1], 0, false);
        pk = __builtin_amdgcn_cvt_pk_fp8_f32(acc[2], acc[3], pk, true);
        *(unsigned int*)(outp + o * 1024) = pk;
    }
}

// ---- K3: fp8 MFMA main. block=(n, 16-o tile); A-frags global->reg; x3l dbuf fp8.
#define STAGE1(S, BUF) do {                                                              \
    const unsigned char* wp_ = w3f + ((S) * 8 + ot) * 512 + lane * 8;                    \
    i64 bw0_ = *(const i64*)(wp_);                                                       \
    i64 bw1_ = *(const i64*)(wp_ + 2048);                                                \
    float bias_ = b3l[(S) * 64 + ot * 16 + l15];                                         \
    _Pragma("unroll")                                                                    \
    for (int i_ = 0; i_ < 4; i_++) {                                                     \
        f32x4 d_ = __builtin_amdgcn_mfma_f32_16x16x32_fp8_fp8(af0[i_], bw0_, zero4, 0, 0, 0); \
        d_ = __builtin_amdgcn_mfma_f32_16x16x32_fp8_fp8(af1[i_], bw1_, d_, 0, 0, 0);     \
        int mf_ = w + 8 * i_;                                                            \
        unsigned int pk_ = __builtin_amdgcn_cvt_pk_fp8_f32(d_[0] + bias_, d_[1] + bias_, 0, false); \
        pk_ = __builtin_amdgcn_cvt_pk_fp8_f32(d_[2] + bias_, d_[3] + bias_, pk_, true);  \
        *(unsigned int*)(x3l[BUF] + l15 * 648 + (mf_ >> 1) * 40 + ((mf_ & 1) << 4) + l4 * 4) = pk_; \
    } } while (0)

#define STAGE2(S, BUF) do {                                                              \
    _Pragma("unroll")                                                                    \
    for (int oj_ = 0; oj_ < 2; oj_++) {                                                  \
        i64 a_ = *(const i64*)(x3l[BUF] + (2 * w + oj_) * 648 + l15 * 40 + l4 * 8);      \
        yacc[oj_ * 2 + 0] = __builtin_amdgcn_mfma_f32_16x16x32_fp8_fp8(a_, badj[(S) * 4 + oj_ * 2 + 0], yacc[oj_ * 2 + 0], 0, 0, 0); \
        yacc[oj_ * 2 + 1] = __builtin_amdgcn_mfma_f32_16x16x32_fp8_fp8(a_, badj[(S) * 4 + oj_ * 2 + 1], yacc[oj_ * 2 + 1], 0, 0, 0); \
    } } while (0)

__launch_bounds__(512, 4)
__global__ void k_main(const unsigned char* __restrict__ xT, const float* __restrict__ b3g,
                       const unsigned char* __restrict__ w3f,
                       const unsigned char* __restrict__ adjf,
                       unsigned char* __restrict__ y8, float* __restrict__ partials) {
    __shared__ unsigned char x3l[2][16 * 648];    // 20,736 B, byte-stride 648 (bank-clean)
    __shared__ unsigned char ylds[8][800];        // per-wave y repack, 6,400 B
    __shared__ float b3l[192];

    int bid = blockIdx.x;                          // 0..511; bid&7 = n&7 -> XCD locality
    int n = bid & 127, ot = bid >> 7;
    int tid = threadIdx.x;
    int w = tid >> 6, lane = tid & 63, l15 = lane & 15, l4 = lane >> 4;
    int oa = ot * 16 + 2 * w;

    if (tid < 192) b3l[tid] = b3g[tid];

    // 12 register-resident adj B-frags (fp8, 24 VGPR): [s][oj][ut]
    i64 badj[12];
    {
        const unsigned char* ap = adjf + (size_t)n * 65536 + (size_t)oa * 1024 + lane * 8;
#pragma unroll
        for (int s = 0; s < 3; s++)
#pragma unroll
            for (int oj = 0; oj < 2; oj++)
#pragma unroll
                for (int ut = 0; ut < 2; ut++)
                    badj[s * 4 + oj * 2 + ut] =
                        *(const i64*)(ap + (size_t)s * 8388608 + oj * 1024 + ut * 512);
    }
    __syncthreads();

    f32x4 zero4 = {0.f, 0.f, 0.f, 0.f};
    float s1[2] = {0.f, 0.f}, s2[2] = {0.f, 0.f};
    const unsigned char* xTn = xT + (size_t)n * 204800;
    int vrow = ((w & 1) << 4) + l15;
    bool vok = vrow < 25;
    int vc = vok ? vrow : 24;

    for (int tc = 0; tc < 8; tc++) {
        // A-frags for this chunk: 4 M-tiles x (K 0-31, 32-63), coalesced global loads
        i64 af0[4], af1[4];
#pragma unroll
        for (int i_ = 0; i_ < 4; i_++) {
            int mf_ = w + 8 * i_;
            int tvk = (mf_ >> 1) * 25 + vc;
            const unsigned char* p = xTn + (size_t)(tc * 400 + tvk) * 64 + l4 * 8;
            i64 a0 = *(const i64*)p;
            i64 a1 = *(const i64*)(p + 32);
            af0[i_] = vok ? a0 : 0;
            af1[i_] = vok ? a1 : 0;
        }
        f32x4 yacc[4] = {zero4, zero4, zero4, zero4};

        STAGE1(0, 0);
        __syncthreads();
        STAGE1(1, 1);
        STAGE2(0, 0);
        __syncthreads();
        STAGE1(2, 0);
        STAGE2(1, 1);
        __syncthreads();
        STAGE2(2, 0);

        // epilogue: stats (f32, pad-u cols exactly 0 via adj zero-pad) + fp8 y repack
#pragma unroll
        for (int oj = 0; oj < 2; oj++) {
#pragma unroll
            for (int ut = 0; ut < 2; ut++) {
                f32x4 d = yacc[oj * 2 + ut];
                int u = ut * 16 + l15;
                s1[oj] += d[0] + d[1] + d[2] + d[3];
                s2[oj] += d[0] * d[0] + d[1] * d[1] + d[2] * d[2] + d[3] * d[3];
                if (u < 25) {
#pragma unroll
                    for (int r = 0; r < 4; r++) {
                        unsigned int b = __builtin_amdgcn_cvt_pk_fp8_f32(d[r], d[r], 0, false) & 0xFFu;
                        ylds[w][oj * 400 + (l4 * 4 + r) * 25 + u] = (unsigned char)b;
                    }
                }
            }
        }
        asm volatile("s_waitcnt lgkmcnt(0)" ::: "memory");
#pragma unroll
        for (int rep = 0; rep < 4; rep++) {
            int idx = lane + rep * 64;
            if (idx < 200) {
                int oj = idx >= 100 ? 1 : 0;
                size_t gb = ((size_t)(n * 64 + oa + oj) * 3200) + tc * 400 + (idx - oj * 100) * 4;
                *(unsigned int*)(y8 + gb) = *(const unsigned int*)(&ylds[w][idx * 4]);
            }
        }
        __syncthreads();
    }

    // deterministic per-(o,n) partials
#pragma unroll
    for (int oj = 0; oj < 2; oj++) {
        float a = s1[oj], b = s2[oj];
#pragma unroll
        for (int off = 1; off < 64; off <<= 1) {
            a += __shfl_xor(a, off);
            b += __shfl_xor(b, off);
        }
        if (lane == 0) {
            partials[((oa + oj) * 2 + 0) * 128 + n] = a;
            partials[((oa + oj) * 2 + 1) * 128 + n] = b;
        }
    }
}

// ---- fused reduce + coef ----
__global__ void k_redcoef(const float* __restrict__ partials, const float* __restrict__ bnw,
                          const float* __restrict__ bnb, float* __restrict__ coef) {
    __shared__ float st[128];
    int tid = threadIdx.x;                   // 128
    const float4* p = (const float4*)(partials + tid * 128);
    float a = 0.f;
#pragma unroll
    for (int i = 0; i < 32; i++) {
        float4 q = p[i];
        a += q.x + q.y + q.z + q.w;
    }
    st[tid] = a;
    __syncthreads();
    if (tid < 64) {
        const float inv = 1.f / 409600.f;
        float mean = st[2 * tid] * inv;
        float var = st[2 * tid + 1] * inv - mean * mean;
        float sc = bnw[tid] * rsqrtf(var + 1e-5f);
        coef[2 * tid] = sc;
        coef[2 * tid + 1] = bnb[tid] - mean * sc;
    }
}

// ---- K5: out = relu(fp8(y)*scale + shift + x) ----
__launch_bounds__(512)
__global__ void k_final(float* __restrict__ outp, const unsigned char* __restrict__ y8,
                        const float* __restrict__ x, const float* __restrict__ coef) {
    unsigned int i = blockIdx.x * 512u + threadIdx.x;   // 6,553,600 quads
    unsigned int o = (i / 800u) & 63u;
    float sc = coef[o * 2], sh = coef[o * 2 + 1];
    unsigned int yw = ((const unsigned int*)y8)[i];
    f32x2 lo = __builtin_amdgcn_cvt_pk_f32_fp8(yw, false);
    f32x2 hi = __builtin_amdgcn_cvt_pk_f32_fp8(yw, true);
    float4 xv = ((const float4*)x)[i];
    float4 r;
    r.x = fmaxf(lo[0] * sc + sh + xv.x, 0.f);
    r.y = fmaxf(lo[1] * sc + sh + xv.y, 0.f);
    r.z = fmaxf(hi[0] * sc + sh + xv.z, 0.f);
    r.w = fmaxf(hi[1] * sc + sh + xv.w, 0.f);
    ((float4*)outp)[i] = r;
}

extern "C" void kernel_launch(void* const* d_in, const int* in_sizes, int n_in,
                              void* d_out, int out_size, void* d_ws, size_t ws_size,
                              hipStream_t stream) {
    const float* x    = (const float*)d_in[0];
    const float* W1   = (const float*)d_in[1];
    const float* b1   = (const float*)d_in[2];
    const float* W2   = (const float*)d_in[3];
    const float* b2   = (const float*)d_in[4];
    const float* W3   = (const float*)d_in[5];
    const float* b3   = (const float*)d_in[6];
    const float* W4   = (const float*)d_in[7];
    const float* b4   = (const float*)d_in[8];
    const float* PA   = (const float*)d_in[9];
    const float* alpha= (const float*)d_in[10];
    const float* bnw  = (const float*)d_in[11];
    const float* bnb  = (const float*)d_in[12];

    char* wsb = (char*)d_ws;
    unsigned char* adjf  = (unsigned char*)(wsb + ADJ8_OFF);
    unsigned char* w3f   = (unsigned char*)(wsb + W3F8_OFF);
    unsigned char* xT    = (unsigned char*)(wsb + XT8_OFF);
    unsigned char* y8    = (unsigned char*)(wsb + Y8_OFF);
    float* xbar     = (float*)(wsb + XBAR_OFF);
    float* partials = (float*)(wsb + PART_OFF);
    float* coef     = (float*)(wsb + COEF_OFF);
    float* outp     = (float*)d_out;

    hipLaunchKernelGGL(k_zero, dim3(800), dim3(256), 0, stream, xbar);
    hipLaunchKernelGGL(k_w3prep, dim3(3), dim3(512), 0, stream, W3, w3f);
    hipLaunchKernelGGL(k_prep, dim3(1024), dim3(512), 0, stream, x, xbar, xT);
    hipLaunchKernelGGL(k_adj, dim3(384), dim3(256), 0, stream,
                       xbar, W1, b1, W2, b2, W4, b4, PA, alpha, adjf);
    hipLaunchKernelGGL(k_main, dim3(512), dim3(512), 0, stream,
                       xT, b3, w3f, adjf, y8, partials);
    hipLaunchKernelGGL(k_redcoef, dim3(1), dim3(128), 0, stream, partials, bnw, bnb, coef);
    hipLaunchKernelGGL(k_final, dim3(12800), dim3(512), 0, stream, outp, y8, x, coef);
}